// Round 8
// baseline (241.361 us; speedup 1.0000x reference)
//
#include <hip/hip_runtime.h>
#include <hip/hip_bf16.h>

#define B_N 4096
#define T_N 64
#define D_N 256
#define H_N 128
#define K_N 12

typedef __attribute__((ext_vector_type(8))) short short8;
typedef __attribute__((ext_vector_type(4))) float f32x4;

static __device__ __forceinline__ unsigned bf16_rne(float x) {
  unsigned u = __float_as_uint(x);
  return (u + 0x7fffu + ((u >> 16) & 1u)) >> 16;
}
static __device__ __forceinline__ unsigned pk2(float a, float b) {
  return bf16_rne(a) | (bf16_rne(b) << 16);
}

// ---------------------------------------------------------------------------
// prep_wa: pack w_atom (fp32 [12][256]) into bf16 B-fragments for
// mfma_f32_16x16x32_bf16.  Fragment for step s (d0=32s): lane l supplies
// B[d = 32s + 8*(l>>4) + j][k = l&15], j=0..7 -> 16B per (s,lane).
// ---------------------------------------------------------------------------
__global__ void prep_wa(const float* __restrict__ w_atom, unsigned* __restrict__ wa_frag) {
  const int tid = blockIdx.x * 64 + threadIdx.x;   // 512 threads
  const int s = tid >> 6, l = tid & 63;
  const int k = l & 15, h = l >> 4, d0 = s * 32 + h * 8;
  unsigned o[4];
#pragma unroll
  for (int j = 0; j < 4; ++j) {
    const float a = (k < K_N) ? w_atom[k * D_N + d0 + 2 * j]     : 0.f;
    const float b = (k < K_N) ? w_atom[k * D_N + d0 + 2 * j + 1] : 0.f;
    o[j] = pk2(a, b);
  }
  *(uint4*)(wa_frag + (size_t)tid * 4) = make_uint4(o[0], o[1], o[2], o[3]);
}

// ---------------------------------------------------------------------------
// K1 (MFMA + register-prefetch pipeline): grid 1024, each block runs NB=4 b's.
// Per iteration:
//   S0: vmcnt(0) (prefetched regs arrived) -> bf16 convert -> swizzled tile
//       lgkmcnt(0); s_barrier            (vmcnt NOT drained at any barrier)
//   S1: issue b+1's 16 global_load_dwordx4 + dx int4 (fly through p1+p2)
//       p1: 8x{ds_read_b128 + mfma_16x16x32_bf16}  -> C[t,k] per wave strip
//       p1.5: wv = valid*sigmoid(C+ba) -> wv32;  lgkmcnt(0); s_barrier
//   S2: p2: wave owns k=3w..3w+2 over all 64 t (wv32 broadcasts + own tile
//       slice), mol store, atom_out store;  lgkmcnt(0); s_barrier
// LDS 35.3KB (tile 32K + wv32 3K) -> 4 blocks/CU; HBM hidden under compute.
// ---------------------------------------------------------------------------
__global__ __launch_bounds__(256) void k1_mol(
    const int* __restrict__ dx, const float* __restrict__ feats,
    const unsigned* __restrict__ wa_frag, const float* __restrict__ b_atom,
    float* __restrict__ out_atom, float* __restrict__ mol)
{
  __shared__ unsigned tile[64 * 128];   // 32 KB bf16 tile, 16B-granule swizzle
  __shared__ float wv32[K_N * 64];

  const int tid  = threadIdx.x;
  const int lane = tid & 63;
  const int w    = tid >> 6;
  const int k    = lane & 15;
  const int h    = lane >> 4;

  // B-fragments (coalesced 16B loads, held in VGPRs for all 4 iterations)
  short8 bfr[8];
  {
    const short8* wf8 = (const short8*)wa_frag;
#pragma unroll
    for (int s = 0; s < 8; ++s) bfr[s] = wf8[s * 64 + lane];
  }
  const float ba = (k < K_N) ? b_atom[k] : 0.f;

  const int b0 = blockIdx.x * 4;

  // ---- prologue: issue loads for first b ----------------------------------
  float4 r[16];
  {
    const float* fg = feats + ((size_t)b0 * 65 + 1) * 256 + (size_t)(w << 4) * 256 + (lane << 2);
#pragma unroll
    for (int i = 0; i < 16; ++i) r[i] = *(const float4*)(fg + i * 256);
  }
  int4 dv = *(const int4*)(dx + b0 * T_N + (w << 4) + (h << 2));

  for (int ib = 0; ib < 4; ++ib) {
    const int b = b0 + ib;

    // ---- S0: regs -> bf16 swizzled tile -----------------------------------
    asm volatile("s_waitcnt vmcnt(0)" ::: "memory");
    __builtin_amdgcn_sched_barrier(0);
#pragma unroll
    for (int i = 0; i < 16; ++i) {
      const int t = (w << 4) + i;
      const unsigned off = t * 128 + (((lane >> 1) ^ i) << 2) + (lane & 1) * 2;
      *(uint2*)&tile[off] = make_uint2(pk2(r[i].x, r[i].y), pk2(r[i].z, r[i].w));
    }
    asm volatile("s_waitcnt lgkmcnt(0)" ::: "memory");
    __builtin_amdgcn_s_barrier();
    __builtin_amdgcn_sched_barrier(0);

    // ---- S1: prefetch next b (loads fly under p1+p2) ----------------------
    int4 dvn = dv;
    if (ib < 3) {
      const float* fg = feats + ((size_t)(b + 1) * 65 + 1) * 256 + (size_t)(w << 4) * 256 + (lane << 2);
#pragma unroll
      for (int i = 0; i < 16; ++i) r[i] = *(const float4*)(fg + i * 256);
      dvn = *(const int4*)(dx + (b + 1) * T_N + (w << 4) + (h << 2));
    }

    // ---- phase 1: C[t,k] via 8 mfma steps ---------------------------------
    f32x4 cacc = {0.f, 0.f, 0.f, 0.f};
#pragma unroll
    for (int s = 0; s < 8; ++s) {
      const unsigned off = ((w << 4) + k) * 128 + (((4 * s + h) ^ k) << 2);
      const short8 afrag = *(const short8*)&tile[off];
      cacc = __builtin_amdgcn_mfma_f32_16x16x32_bf16(afrag, bfr[s], cacc, 0, 0, 0);
    }

    // ---- phase 1.5: wv = valid * sigmoid(C + ba) -> wv32 ------------------
#pragma unroll
    for (int rr = 0; rr < 4; ++rr) {
      const int tl = (h << 2) + rr;
      const float valid = (((const int*)&dv)[rr] != 0) ? 1.f : 0.f;
      const float wvv = valid / (1.f + __expf(-(cacc[rr] + ba)));
      if (k < K_N) wv32[k * 64 + (w << 4) + tl] = wvv;
    }
    asm volatile("s_waitcnt lgkmcnt(0)" ::: "memory");
    __builtin_amdgcn_s_barrier();
    __builtin_amdgcn_sched_barrier(0);

    // ---- S2 / phase 2: mol[k][d] over all t; wave owns k=3w..3w+2 ---------
    const int kb = w * 3;
    float4 m0 = make_float4(0.f, 0.f, 0.f, 0.f), m1 = m0, m2 = m0;
#pragma unroll
    for (int tc = 0; tc < 16; ++tc) {
      const float4 wv0 = *(const float4*)&wv32[(kb + 0) * 64 + (tc << 2)];
      const float4 wv1 = *(const float4*)&wv32[(kb + 1) * 64 + (tc << 2)];
      const float4 wv2 = *(const float4*)&wv32[(kb + 2) * 64 + (tc << 2)];
      const float w0a[4] = {wv0.x, wv0.y, wv0.z, wv0.w};
      const float w1a[4] = {wv1.x, wv1.y, wv1.z, wv1.w};
      const float w2a[4] = {wv2.x, wv2.y, wv2.z, wv2.w};
#pragma unroll
      for (int j = 0; j < 4; ++j) {
        const int t = (tc << 2) + j;
        const unsigned off = t * 128 + (((lane >> 1) ^ (t & 15)) << 2) + (lane & 1) * 2;
        const uint2 pw = *(const uint2*)&tile[off];
        const float f0 = __uint_as_float(pw.x << 16);
        const float f1 = __uint_as_float(pw.x & 0xffff0000u);
        const float f2 = __uint_as_float(pw.y << 16);
        const float f3 = __uint_as_float(pw.y & 0xffff0000u);
        m0.x = fmaf(w0a[j], f0, m0.x); m0.y = fmaf(w0a[j], f1, m0.y);
        m0.z = fmaf(w0a[j], f2, m0.z); m0.w = fmaf(w0a[j], f3, m0.w);
        m1.x = fmaf(w1a[j], f0, m1.x); m1.y = fmaf(w1a[j], f1, m1.y);
        m1.z = fmaf(w1a[j], f2, m1.z); m1.w = fmaf(w1a[j], f3, m1.w);
        m2.x = fmaf(w2a[j], f0, m2.x); m2.y = fmaf(w2a[j], f1, m2.y);
        m2.z = fmaf(w2a[j], f2, m2.z); m2.w = fmaf(w2a[j], f3, m2.w);
      }
    }
    float* mp = mol + ((size_t)kb * B_N + b) * D_N + (lane << 2);
    *(float4*)(mp) = m0;
    *(float4*)(mp + (size_t)B_N * D_N) = m1;
    *(float4*)(mp + (size_t)2 * B_N * D_N) = m2;

    if (tid < 192) {
      const float4 v = *(const float4*)&wv32[tid * 4];
      const int kk = tid >> 4, t0 = (tid & 15) * 4;
      *(float4*)&out_atom[((size_t)kk * B_N + b) * T_N + t0] = v;
    }
    dv = dvn;

    asm volatile("s_waitcnt lgkmcnt(0)" ::: "memory");
    __builtin_amdgcn_s_barrier();
    __builtin_amdgcn_sched_barrier(0);
  }
}

// ---------------------------------------------------------------------------
// GEMM: Out = relu( (A [*alpha+beta]) @ W + bias ), plus per-(k,h) sum/sumsq
// stats via atomics.  Tile 64(b) x 128(h), 256 threads, 4x8 micro-tile.
// ---------------------------------------------------------------------------
template <int DIN>
__global__ __launch_bounds__(256) void gemm_bn(
    const float* __restrict__ A, const float* __restrict__ W,
    const float* __restrict__ bias, const float* __restrict__ alpha,
    const float* __restrict__ beta, float* __restrict__ Out,
    float* __restrict__ ssum, float* __restrict__ ssq)
{
  const int k  = blockIdx.y;
  const int b0 = blockIdx.x << 6;
  const int tid = threadIdx.x;
  const int tx = tid & 15, ty = tid >> 4;

  __shared__ float AsT[16][68];
  __shared__ float Bs[16][128];
  __shared__ float red[2][16][128];

  const float* Ak = A + (size_t)k * B_N * DIN;
  const float* Wk = W + (size_t)k * DIN * H_N;

  float acc[4][8];
#pragma unroll
  for (int r = 0; r < 4; ++r)
#pragma unroll
    for (int c = 0; c < 8; ++c) acc[r][c] = 0.f;

  const int ar_ = tid >> 2, ac4 = tid & 3;
  const int wr_ = tid >> 5, wc4 = tid & 31;

  for (int kd0 = 0; kd0 < DIN; kd0 += 16) {
    float4 av = *(const float4*)(Ak + (size_t)(b0 + ar_) * DIN + kd0 + (ac4 << 2));
    if (alpha != nullptr) {
      const float4 al = *(const float4*)(alpha + k * DIN + kd0 + (ac4 << 2));
      const float4 bb = *(const float4*)(beta  + k * DIN + kd0 + (ac4 << 2));
      av.x = fmaf(av.x, al.x, bb.x);
      av.y = fmaf(av.y, al.y, bb.y);
      av.z = fmaf(av.z, al.z, bb.z);
      av.w = fmaf(av.w, al.w, bb.w);
    }
    const float4 wv0 = *(const float4*)(Wk + (size_t)(kd0 + wr_) * H_N + (wc4 << 2));
    const float4 wv1 = *(const float4*)(Wk + (size_t)(kd0 + 8 + wr_) * H_N + (wc4 << 2));
    __syncthreads();
    AsT[(ac4 << 2) + 0][ar_] = av.x;
    AsT[(ac4 << 2) + 1][ar_] = av.y;
    AsT[(ac4 << 2) + 2][ar_] = av.z;
    AsT[(ac4 << 2) + 3][ar_] = av.w;
    *(float4*)&Bs[wr_][wc4 << 2]     = wv0;
    *(float4*)&Bs[8 + wr_][wc4 << 2] = wv1;
    __syncthreads();
#pragma unroll
    for (int kk = 0; kk < 16; ++kk) {
      const float4 a4  = *(const float4*)&AsT[kk][ty << 2];
      const float4 bv0 = *(const float4*)&Bs[kk][tx << 3];
      const float4 bv1 = *(const float4*)&Bs[kk][(tx << 3) + 4];
      const float ar[4] = {a4.x, a4.y, a4.z, a4.w};
      const float br[8] = {bv0.x, bv0.y, bv0.z, bv0.w, bv1.x, bv1.y, bv1.z, bv1.w};
#pragma unroll
      for (int r = 0; r < 4; ++r)
#pragma unroll
        for (int c = 0; c < 8; ++c) acc[r][c] = fmaf(ar[r], br[c], acc[r][c]);
    }
  }

  const float4 bi0 = *(const float4*)(bias + k * H_N + (tx << 3));
  const float4 bi1 = *(const float4*)(bias + k * H_N + (tx << 3) + 4);
  const float bb[8] = {bi0.x, bi0.y, bi0.z, bi0.w, bi1.x, bi1.y, bi1.z, bi1.w};
  float cs[8], cq[8];
#pragma unroll
  for (int c = 0; c < 8; ++c) { cs[c] = 0.f; cq[c] = 0.f; }
#pragma unroll
  for (int r = 0; r < 4; ++r) {
    const int b = b0 + (ty << 2) + r;
    float o[8];
#pragma unroll
    for (int c = 0; c < 8; ++c) {
      o[c] = fmaxf(acc[r][c] + bb[c], 0.f);
      cs[c] += o[c];
      cq[c] = fmaf(o[c], o[c], cq[c]);
    }
    float* op = Out + ((size_t)k * B_N + b) * H_N + (tx << 3);
    *(float4*)op       = make_float4(o[0], o[1], o[2], o[3]);
    *(float4*)(op + 4) = make_float4(o[4], o[5], o[6], o[7]);
  }
#pragma unroll
  for (int c = 0; c < 8; ++c) {
    red[0][ty][(tx << 3) + c] = cs[c];
    red[1][ty][(tx << 3) + c] = cq[c];
  }
  __syncthreads();
  if (tid < H_N) {
    float s = 0.f, q = 0.f;
#pragma unroll
    for (int i = 0; i < 16; ++i) { s += red[0][i][tid]; q += red[1][i][tid]; }
    atomicAdd(&ssum[k * H_N + tid], s);
    atomicAdd(&ssq[k * H_N + tid], q);
  }
}

// stats -> alpha/beta
__global__ void bn_coef(const float* __restrict__ ssum, const float* __restrict__ ssq,
                        const float* __restrict__ g, const float* __restrict__ be,
                        float* __restrict__ alpha, float* __restrict__ beta)
{
  const int i = blockIdx.x * 256 + threadIdx.x;
  if (i >= K_N * H_N) return;
  const float inv_n = 1.f / (float)B_N;
  const float m = ssum[i] * inv_n;
  float v = fmaf(ssq[i], inv_n, -m * m);
  v = fmaxf(v, 0.f);
  const float a = g[i] * rsqrtf(v + 1e-5f);
  alpha[i] = a;
  beta[i]  = fmaf(-m, a, be[i]);
}

// final: pred[b,k] = dot(a3*alpha+beta, Wout) + bout  (one wave per (b,k))
__global__ __launch_bounds__(256) void k_pred(
    const float* __restrict__ a3, const float* __restrict__ alpha,
    const float* __restrict__ beta, const float* __restrict__ Wout,
    const float* __restrict__ bout, float* __restrict__ out)
{
  const int lane = threadIdx.x & 63;
  const int wv   = threadIdx.x >> 6;
  const int pair = blockIdx.x * 4 + wv;
  const int b = pair / K_N, k = pair - b * K_N;
  const float2 x  = *(const float2*)(a3 + ((size_t)k * B_N + b) * H_N + (lane << 1));
  const float2 al = *(const float2*)(alpha + k * H_N + (lane << 1));
  const float2 be = *(const float2*)(beta  + k * H_N + (lane << 1));
  const float2 wo = *(const float2*)(Wout  + k * H_N + (lane << 1));
  float s = fmaf(x.x, al.x, be.x) * wo.x + fmaf(x.y, al.y, be.y) * wo.y;
#pragma unroll
  for (int off = 32; off; off >>= 1) s += __shfl_down(s, off);
  if (lane == 0) out[pair] = s + bout[k];
}

extern "C" void kernel_launch(void* const* d_in, const int* in_sizes, int n_in,
                              void* d_out, int out_size, void* d_ws, size_t ws_size,
                              hipStream_t stream)
{
  (void)in_sizes; (void)n_in; (void)out_size; (void)ws_size;
  const int*   dx     = (const int*)d_in[0];
  const float* feats  = (const float*)d_in[1];
  const float* w_atom = (const float*)d_in[2];
  const float* b_atom = (const float*)d_in[3];
  const float* W1 = (const float*)d_in[4];
  const float* b1 = (const float*)d_in[5];
  const float* g1 = (const float*)d_in[6];
  const float* be1 = (const float*)d_in[7];
  const float* W2 = (const float*)d_in[8];
  const float* b2 = (const float*)d_in[9];
  const float* g2 = (const float*)d_in[10];
  const float* be2 = (const float*)d_in[11];
  const float* W3 = (const float*)d_in[12];
  const float* b3 = (const float*)d_in[13];
  const float* g3 = (const float*)d_in[14];
  const float* be3 = (const float*)d_in[15];
  const float* Wout = (const float*)d_in[16];
  const float* bout = (const float*)d_in[17];

  float* out      = (float*)d_out;
  float* pred_out = out;                       // (B, K) = 49152
  float* atom_out = out + (size_t)B_N * K_N;   // (K, B, T)

  float* ws  = (float*)d_ws;
  float* mol = ws;                                        // K*B*D
  float* a1  = ws + (size_t)K_N * B_N * D_N;              // K*B*H
  float* a2  = a1 + (size_t)K_N * B_N * H_N;
  float* a3  = ws;                                        // alias mol (dead after layer 1)
  float* st  = a2 + (size_t)K_N * B_N * H_N;              // stats base
  float* s1 = st,          *q1 = st + 1536;
  float* s2 = st + 3072,   *q2 = st + 4608;
  float* s3 = st + 6144,   *q3 = st + 7680;
  float* ab  = st + 9216;
  float* al1 = ab,          *bt1 = ab + 1536;
  float* al2 = ab + 3072,   *bt2 = ab + 4608;
  float* al3 = ab + 6144,   *bt3 = ab + 7680;
  unsigned* wa_frag = (unsigned*)(ab + 9216);             // 8*64*4 u32

  hipMemsetAsync(st, 0, 6 * 1536 * sizeof(float), stream);

  prep_wa<<<8, 64, 0, stream>>>(w_atom, wa_frag);
  k1_mol<<<B_N / 4, 256, 0, stream>>>(dx, feats, wa_frag, b_atom, atom_out, mol);
  gemm_bn<256><<<dim3(64, 12), 256, 0, stream>>>(mol, W1, b1, nullptr, nullptr, a1, s1, q1);
  bn_coef<<<6, 256, 0, stream>>>(s1, q1, g1, be1, al1, bt1);
  gemm_bn<128><<<dim3(64, 12), 256, 0, stream>>>(a1, W2, b2, al1, bt1, a2, s2, q2);
  bn_coef<<<6, 256, 0, stream>>>(s2, q2, g2, be2, al2, bt2);
  gemm_bn<128><<<dim3(64, 12), 256, 0, stream>>>(a2, W3, b3, al2, bt2, a3, s3, q3);
  bn_coef<<<6, 256, 0, stream>>>(s3, q3, g3, be3, al3, bt3);
  k_pred<<<B_N * K_N / 4, 256, 0, stream>>>(a3, al3, bt3, Wout, bout, pred_out);
}

// Round 9
// 146.229 us; speedup vs baseline: 1.6506x; 1.6506x over previous
//
#include <hip/hip_runtime.h>
#include <hip/hip_bf16.h>

#define B_N 4096
#define T_N 64
#define D_N 256
#define H_N 128
#define K_N 12

typedef __attribute__((ext_vector_type(8))) short short8;
typedef __attribute__((ext_vector_type(4))) float f32x4;

static __device__ __forceinline__ unsigned bf16_rne(float x) {
  unsigned u = __float_as_uint(x);
  return (u + 0x7fffu + ((u >> 16) & 1u)) >> 16;
}
static __device__ __forceinline__ unsigned pk2(float a, float b) {
  return bf16_rne(a) | (bf16_rne(b) << 16);
}
static __device__ __forceinline__ float lo16(unsigned u) { return __uint_as_float(u << 16); }
static __device__ __forceinline__ float hi16(unsigned u) { return __uint_as_float(u & 0xffff0000u); }

// ---------------------------------------------------------------------------
// prep_wa: pack w_atom into bf16 B-fragments (verified layout from R7).
// ---------------------------------------------------------------------------
__global__ void prep_wa(const float* __restrict__ w_atom, unsigned* __restrict__ wa_frag) {
  const int tid = blockIdx.x * 64 + threadIdx.x;   // 512 threads
  const int s = tid >> 6, l = tid & 63;
  const int k = l & 15, h = l >> 4, d0 = s * 32 + h * 8;
  unsigned o[4];
#pragma unroll
  for (int j = 0; j < 4; ++j) {
    const float a = (k < K_N) ? w_atom[k * D_N + d0 + 2 * j]     : 0.f;
    const float b = (k < K_N) ? w_atom[k * D_N + d0 + 2 * j + 1] : 0.f;
    o[j] = pk2(a, b);
  }
  *(uint4*)(wa_frag + (size_t)tid * 4) = make_uint4(o[0], o[1], o[2], o[3]);
}

// ---------------------------------------------------------------------------
// prep_w: pack layer weight W[k][D][H_N] (D=32*S) into bf16 B-fragments.
// frag idx = ((k*8 + nt)*S + s)*64 + lane; elems j=0..7:
//   B[d = 32s + 8*(lane>>4) + j][n = nt*16 + (lane&15)]
// ---------------------------------------------------------------------------
__global__ void prep_w(const float* __restrict__ W, unsigned* __restrict__ out, int S) {
  const int id = blockIdx.x * 256 + threadIdx.x;
  const int total = K_N * 8 * S * 64;
  if (id >= total) return;
  const int lane = id & 63;
  const int s  = (id >> 6) % S;
  const int nt = ((id >> 6) / S) & 7;
  const int kk = id / (64 * S * 8);
  const int n  = nt * 16 + (lane & 15);
  const int d0 = 32 * s + 8 * (lane >> 4);
  const int D  = 32 * S;
  unsigned o[4];
#pragma unroll
  for (int j = 0; j < 4; ++j) {
    const float a = W[(size_t)kk * D * H_N + (d0 + 2 * j) * H_N + n];
    const float b = W[(size_t)kk * D * H_N + (d0 + 2 * j + 1) * H_N + n];
    o[j] = pk2(a, b);
  }
  *(uint4*)(out + (size_t)id * 4) = make_uint4(o[0], o[1], o[2], o[3]);
}

// ---------------------------------------------------------------------------
// K1 (R7 structure, mol stored bf16): one block per b, 4 waves, 35.3KB LDS.
// ---------------------------------------------------------------------------
__global__ __launch_bounds__(256) void k1_mol(
    const int* __restrict__ dx, const float* __restrict__ feats,
    const unsigned* __restrict__ wa_frag, const float* __restrict__ b_atom,
    float* __restrict__ out_atom, unsigned* __restrict__ molb)
{
  __shared__ unsigned tile[64 * 128];   // 32 KB bf16 tile, 16B-granule swizzle
  __shared__ float dxv[64];
  __shared__ float wv32[K_N * 64];

  const int tid  = threadIdx.x;
  const int lane = tid & 63;
  const int w    = tid >> 6;
  const int b    = blockIdx.x;
  const int k    = lane & 15;
  const int h    = lane >> 4;

  short8 bfr[8];
  {
    const short8* wf8 = (const short8*)wa_frag;
#pragma unroll
    for (int s = 0; s < 8; ++s) bfr[s] = wf8[s * 64 + lane];
  }
  const float ba = (k < K_N) ? b_atom[k] : 0.f;
  if (tid < 64) dxv[tid] = (dx[b * T_N + tid] != 0) ? 1.f : 0.f;

  const float* fg = feats + ((size_t)b * 65 + 1) * 256;
#pragma unroll
  for (int c = 0; c < 4; ++c) {
    float4 v[4];
#pragma unroll
    for (int i = 0; i < 4; ++i)
      v[i] = *(const float4*)(fg + (size_t)(16 * w + 4 * c + i) * 256 + 4 * lane);
#pragma unroll
    for (int i = 0; i < 4; ++i) {
      const int tl = 4 * c + i;
      const int t  = 16 * w + tl;
      const unsigned off = t * 128 + (((lane >> 1) ^ tl) << 2) + (lane & 1) * 2;
      *(uint2*)&tile[off] = make_uint2(pk2(v[i].x, v[i].y), pk2(v[i].z, v[i].w));
    }
  }
  __syncthreads();

  f32x4 cacc = {0.f, 0.f, 0.f, 0.f};
#pragma unroll
  for (int s = 0; s < 8; ++s) {
    const unsigned off = (16 * w + k) * 128 + (((4 * s + h) ^ k) << 2);
    const short8 afrag = *(const short8*)&tile[off];
    cacc = __builtin_amdgcn_mfma_f32_16x16x32_bf16(afrag, bfr[s], cacc, 0, 0, 0);
  }

#pragma unroll
  for (int r = 0; r < 4; ++r) {
    const int tl = 4 * h + r;
    const float valid = dxv[16 * w + tl];
    const float wv = valid / (1.f + __expf(-(cacc[r] + ba)));
    if (k < K_N) wv32[k * 64 + 16 * w + tl] = wv;
  }
  __syncthreads();

  const int kb = w * 3;
  float4 m0 = make_float4(0.f, 0.f, 0.f, 0.f), m1 = m0, m2 = m0;
#pragma unroll
  for (int tc = 0; tc < 16; ++tc) {
    const float4 wv0 = *(const float4*)&wv32[(kb + 0) * 64 + (tc << 2)];
    const float4 wv1 = *(const float4*)&wv32[(kb + 1) * 64 + (tc << 2)];
    const float4 wv2 = *(const float4*)&wv32[(kb + 2) * 64 + (tc << 2)];
    const float w0a[4] = {wv0.x, wv0.y, wv0.z, wv0.w};
    const float w1a[4] = {wv1.x, wv1.y, wv1.z, wv1.w};
    const float w2a[4] = {wv2.x, wv2.y, wv2.z, wv2.w};
#pragma unroll
    for (int j = 0; j < 4; ++j) {
      const int t = (tc << 2) + j;
      const unsigned off = t * 128 + (((lane >> 1) ^ (t & 15)) << 2) + (lane & 1) * 2;
      const uint2 pw = *(const uint2*)&tile[off];
      const float f0 = lo16(pw.x), f1 = hi16(pw.x);
      const float f2 = lo16(pw.y), f3 = hi16(pw.y);
      m0.x = fmaf(w0a[j], f0, m0.x); m0.y = fmaf(w0a[j], f1, m0.y);
      m0.z = fmaf(w0a[j], f2, m0.z); m0.w = fmaf(w0a[j], f3, m0.w);
      m1.x = fmaf(w1a[j], f0, m1.x); m1.y = fmaf(w1a[j], f1, m1.y);
      m1.z = fmaf(w1a[j], f2, m1.z); m1.w = fmaf(w1a[j], f3, m1.w);
      m2.x = fmaf(w2a[j], f0, m2.x); m2.y = fmaf(w2a[j], f1, m2.y);
      m2.z = fmaf(w2a[j], f2, m2.z); m2.w = fmaf(w2a[j], f3, m2.w);
    }
  }
  // mol stored as bf16 [k][b][d]; lane owns d=4*lane..+3 -> one uint2
  unsigned* mpb = molb + ((size_t)kb * B_N + b) * 128 + (lane << 1);
  *(uint2*)(mpb)                      = make_uint2(pk2(m0.x, m0.y), pk2(m0.z, m0.w));
  *(uint2*)(mpb + (size_t)B_N * 128)  = make_uint2(pk2(m1.x, m1.y), pk2(m1.z, m1.w));
  *(uint2*)(mpb + (size_t)2 * B_N * 128) = make_uint2(pk2(m2.x, m2.y), pk2(m2.z, m2.w));

  if (tid < 192) {
    const float4 v = *(const float4*)&wv32[tid * 4];
    const int kk = tid >> 4, t0 = (tid & 15) * 4;
    *(float4*)&out_atom[((size_t)kk * B_N + b) * T_N + t0] = v;
  }
}

// ---------------------------------------------------------------------------
// MFMA GEMM layer: H = relu( (A[*al+bt]) @ W + bias ), A bf16 [k][B][D],
// W pre-packed B-frags, H stored bf16, per-(k,h) sum/sumsq stats.
// Block: 64 b-rows x 128 h-cols, 4 waves (16 rows each), 8 n-tiles/wave.
// S = K/32 (8 for D=256, 4 for D=128).  AFFINE: apply al/bt on A load.
// ---------------------------------------------------------------------------
template <int S, bool AFFINE>
__global__ __launch_bounds__(256) void gemm_mfma(
    const unsigned* __restrict__ Abf, const unsigned* __restrict__ wpack,
    const float* __restrict__ bias, const float* __restrict__ alpha,
    const float* __restrict__ beta, unsigned short* __restrict__ Hout,
    float* __restrict__ ssum, float* __restrict__ ssq)
{
  __shared__ unsigned tile[64 * S * 16];       // 64 rows x K bf16, swizzled
  __shared__ float redS[4][8][16];
  __shared__ float redQ[4][8][16];

  const int k   = blockIdx.y;
  const int b0  = blockIdx.x << 6;
  const int tid = threadIdx.x;
  const int lane = tid & 63;
  const int wv  = tid >> 6;
  const int ln15 = lane & 15;
  const int hq   = lane >> 4;

  // ---- stage A: thread t -> row t>>2, granules (t&3)*S .. +S-1 ------------
  {
    const int row = tid >> 2, q = tid & 3;
    const uint4* Ar = (const uint4*)Abf + ((size_t)k * B_N + b0 + row) * (S * 4) + q * S;
#pragma unroll
    for (int gi = 0; gi < S; ++gi) {
      const int g = q * S + gi;
      uint4 u = Ar[gi];
      if (AFFINE) {
        const float4 al0 = *(const float4*)(alpha + k * H_N + g * 8);
        const float4 al1 = *(const float4*)(alpha + k * H_N + g * 8 + 4);
        const float4 bt0 = *(const float4*)(beta  + k * H_N + g * 8);
        const float4 bt1 = *(const float4*)(beta  + k * H_N + g * 8 + 4);
        u.x = pk2(fmaf(lo16(u.x), al0.x, bt0.x), fmaf(hi16(u.x), al0.y, bt0.y));
        u.y = pk2(fmaf(lo16(u.y), al0.z, bt0.z), fmaf(hi16(u.y), al0.w, bt0.w));
        u.z = pk2(fmaf(lo16(u.z), al1.x, bt1.x), fmaf(hi16(u.z), al1.y, bt1.y));
        u.w = pk2(fmaf(lo16(u.w), al1.z, bt1.z), fmaf(hi16(u.w), al1.w, bt1.w));
      }
      *(uint4*)&tile[row * (S * 16) + ((g ^ (row & 15)) << 2)] = u;
    }
  }
  __syncthreads();

  // ---- MFMA main loop: 8 n-tiles, S k-steps, B double-buffered ------------
  const short8* wp8 = (const short8*)wpack + (size_t)k * 8 * S * 64 + lane;
  f32x4 acc[8];
#pragma unroll
  for (int nt = 0; nt < 8; ++nt) acc[nt] = (f32x4){0.f, 0.f, 0.f, 0.f};

  short8 bs0[8], bs1[8];
#pragma unroll
  for (int nt = 0; nt < 8; ++nt) bs0[nt] = wp8[(nt * S) * 64];
#pragma unroll
  for (int s = 0; s < S; ++s) {
    if (s + 1 < S) {
#pragma unroll
      for (int nt = 0; nt < 8; ++nt) {
        if (s & 1) bs0[nt] = wp8[(nt * S + s + 1) * 64];
        else       bs1[nt] = wp8[(nt * S + s + 1) * 64];
      }
    }
    const int arow = (wv << 4) + ln15;
    const unsigned aoff = arow * (S * 16) + (((4 * s + hq) ^ ln15) << 2);
    const short8 af = *(const short8*)&tile[aoff];
#pragma unroll
    for (int nt = 0; nt < 8; ++nt) {
      const short8 bf = (s & 1) ? bs1[nt] : bs0[nt];
      acc[nt] = __builtin_amdgcn_mfma_f32_16x16x32_bf16(af, bf, acc[nt], 0, 0, 0);
    }
  }

  // ---- epilogue: bias+relu, stats, bf16 store -----------------------------
#pragma unroll
  for (int nt = 0; nt < 8; ++nt) {
    const int col = nt * 16 + ln15;
    const float bv = bias[k * H_N + col];
    float cs = 0.f, cq = 0.f;
#pragma unroll
    for (int r = 0; r < 4; ++r) {
      const float o = fmaxf(acc[nt][r] + bv, 0.f);
      cs += o; cq = fmaf(o, o, cq);
      const int row = b0 + (wv << 4) + (hq << 2) + r;
      Hout[((size_t)k * B_N + row) * H_N + col] = (unsigned short)bf16_rne(o);
    }
    cs += __shfl_xor(cs, 16); cs += __shfl_xor(cs, 32);
    cq += __shfl_xor(cq, 16); cq += __shfl_xor(cq, 32);
    if (lane < 16) { redS[wv][nt][ln15] = cs; redQ[wv][nt][ln15] = cq; }
  }
  __syncthreads();
  if (tid < 128) {
    const int nt = tid >> 4, c = tid & 15;
    float s = 0.f, q = 0.f;
#pragma unroll
    for (int i = 0; i < 4; ++i) { s += redS[i][nt][c]; q += redQ[i][nt][c]; }
    atomicAdd(&ssum[k * H_N + nt * 16 + c], s);
    atomicAdd(&ssq[k * H_N + nt * 16 + c], q);
  }
}

// stats -> alpha/beta
__global__ void bn_coef(const float* __restrict__ ssum, const float* __restrict__ ssq,
                        const float* __restrict__ g, const float* __restrict__ be,
                        float* __restrict__ alpha, float* __restrict__ beta)
{
  const int i = blockIdx.x * 256 + threadIdx.x;
  if (i >= K_N * H_N) return;
  const float inv_n = 1.f / (float)B_N;
  const float m = ssum[i] * inv_n;
  float v = fmaf(ssq[i], inv_n, -m * m);
  v = fmaxf(v, 0.f);
  const float a = g[i] * rsqrtf(v + 1e-5f);
  alpha[i] = a;
  beta[i]  = fmaf(-m, a, be[i]);
}

// final: pred[b,k] = dot(h3*al+bt, Wout) + bout  (one wave per (b,k); h3 bf16)
__global__ __launch_bounds__(256) void k_pred(
    const unsigned* __restrict__ h3, const float* __restrict__ alpha,
    const float* __restrict__ beta, const float* __restrict__ Wout,
    const float* __restrict__ bout, float* __restrict__ out)
{
  const int lane = threadIdx.x & 63;
  const int wv   = threadIdx.x >> 6;
  const int pair = blockIdx.x * 4 + wv;
  const int b = pair / K_N, k = pair - b * K_N;
  const unsigned xp = h3[((size_t)k * B_N + b) * 64 + lane];
  const float2 al = *(const float2*)(alpha + k * H_N + (lane << 1));
  const float2 be = *(const float2*)(beta  + k * H_N + (lane << 1));
  const float2 wo = *(const float2*)(Wout  + k * H_N + (lane << 1));
  float s = fmaf(lo16(xp), al.x, be.x) * wo.x + fmaf(hi16(xp), al.y, be.y) * wo.y;
#pragma unroll
  for (int off = 32; off; off >>= 1) s += __shfl_down(s, off);
  if (lane == 0) out[pair] = s + bout[k];
}

extern "C" void kernel_launch(void* const* d_in, const int* in_sizes, int n_in,
                              void* d_out, int out_size, void* d_ws, size_t ws_size,
                              hipStream_t stream)
{
  (void)in_sizes; (void)n_in; (void)out_size; (void)ws_size;
  const int*   dx     = (const int*)d_in[0];
  const float* feats  = (const float*)d_in[1];
  const float* w_atom = (const float*)d_in[2];
  const float* b_atom = (const float*)d_in[3];
  const float* W1 = (const float*)d_in[4];
  const float* b1 = (const float*)d_in[5];
  const float* g1 = (const float*)d_in[6];
  const float* be1 = (const float*)d_in[7];
  const float* W2 = (const float*)d_in[8];
  const float* b2 = (const float*)d_in[9];
  const float* g2 = (const float*)d_in[10];
  const float* be2 = (const float*)d_in[11];
  const float* W3 = (const float*)d_in[12];
  const float* b3 = (const float*)d_in[13];
  const float* g3 = (const float*)d_in[14];
  const float* be3 = (const float*)d_in[15];
  const float* Wout = (const float*)d_in[16];
  const float* bout = (const float*)d_in[17];

  float* out      = (float*)d_out;
  float* pred_out = out;                       // (B, K)
  float* atom_out = out + (size_t)B_N * K_N;   // (K, B, T)

  // ---- workspace layout (bytes) ----
  char* wsb = (char*)d_ws;
  unsigned*       molb = (unsigned*)wsb;                       // 25165824 B (bf16 K*B*D)
  unsigned short* h1   = (unsigned short*)(wsb + 25165824);    // 12582912 B
  unsigned short* h2   = (unsigned short*)(wsb + 37748736);
  unsigned short* h3   = (unsigned short*)(wsb + 50331648);
  float* st = (float*)(wsb + 62914560);                        // stats: 6*1536 f
  float* s1 = st,        *q1 = st + 1536;
  float* s2 = st + 3072, *q2 = st + 4608;
  float* s3 = st + 6144, *q3 = st + 7680;
  float* ab = st + 9216;                                       // al/bt: 6*1536 f
  float* al1 = ab,        *bt1 = ab + 1536;
  float* al2 = ab + 3072, *bt2 = ab + 4608;
  float* al3 = ab + 6144, *bt3 = ab + 7680;
  unsigned* wa_frag = (unsigned*)(ab + 9216);                  // 8192 B
  unsigned* w1p = wa_frag + 2048;                              // 786432 B
  unsigned* w2p = w1p + 196608;                                // 393216 B
  unsigned* w3p = w2p + 98304;                                 // 393216 B

  hipMemsetAsync(st, 0, 6 * 1536 * sizeof(float), stream);

  prep_wa<<<8, 64, 0, stream>>>(w_atom, wa_frag);
  prep_w<<<(K_N * 8 * 8 * 64 + 255) / 256, 256, 0, stream>>>(W1, w1p, 8);
  prep_w<<<(K_N * 8 * 4 * 64 + 255) / 256, 256, 0, stream>>>(W2, w2p, 4);
  prep_w<<<(K_N * 8 * 4 * 64 + 255) / 256, 256, 0, stream>>>(W3, w3p, 4);

  k1_mol<<<B_N, 256, 0, stream>>>(dx, feats, wa_frag, b_atom, atom_out, molb);

  gemm_mfma<8, false><<<dim3(64, 12), 256, 0, stream>>>(
      molb, w1p, b1, nullptr, nullptr, h1, s1, q1);
  bn_coef<<<6, 256, 0, stream>>>(s1, q1, g1, be1, al1, bt1);
  gemm_mfma<4, true><<<dim3(64, 12), 256, 0, stream>>>(
      (const unsigned*)h1, w2p, b2, al1, bt1, h2, s2, q2);
  bn_coef<<<6, 256, 0, stream>>>(s2, q2, g2, be2, al2, bt2);
  gemm_mfma<4, true><<<dim3(64, 12), 256, 0, stream>>>(
      (const unsigned*)h2, w3p, b3, al2, bt2, h3, s3, q3);
  bn_coef<<<6, 256, 0, stream>>>(s3, q3, g3, be3, al3, bt3);
  k_pred<<<B_N * K_N / 4, 256, 0, stream>>>(
      (const unsigned*)h3, al3, bt3, Wout, bout, pred_out);
}